// Round 7
// baseline (5657.176 us; speedup 1.0000x reference)
//
#include <hip/hip_runtime.h>
#include <hip/hip_bf16.h>

// L=512, B=64, D=H=512, 3H=1536.
//  gemm_k<SPLIT,TANH>: Pt/Qt = tanh(v@Wp^T)  (split-bf16 3-pass MFMA)
//  att_k: logits via tanh addition formula, softmax, c = a·v  (c bf16)
//  gemm_k<AIN,BIAS,OUTBF16>: Gi = c@W_ih^T + b_ih
//  rec_k v5: 64 blocks, deterministic XCD grouping (r6-proven preamble),
//    8 groups x 8 blocks x 4 waves. NEW: wave-autonomous per-step sync —
//    per-wave vmcnt drain + one L2 atomic add (target 32), plain-sc0-load
//    polling (no RMW, no sleep), NO __syncthreads in the steady loop.
//    Watchdog+demote (wave-level) keeps every poll target reachable.

typedef float f32x4 __attribute__((ext_vector_type(4)));
typedef short s16x8 __attribute__((ext_vector_type(8)));
typedef short s16x4 __attribute__((ext_vector_type(4)));
typedef unsigned int u32x2 __attribute__((ext_vector_type(2)));

static __device__ __forceinline__ float rcp_fast(float x) { return __builtin_amdgcn_rcpf(x); }
static __device__ __forceinline__ float tanh_fast(float x) {
    float e = __expf(2.0f * x);
    return 1.0f - 2.0f * rcp_fast(e + 1.0f);
}
static __device__ __forceinline__ float sigmoid_fast(float x) {
    return rcp_fast(1.0f + __expf(-x));
}
static __device__ __forceinline__ unsigned short f2bf(float x) {
    union { float f; unsigned u; } v; v.f = x;
    unsigned r = v.u + 0x7FFFu + ((v.u >> 16) & 1u);
    return (unsigned short)(r >> 16);
}
static __device__ __forceinline__ float bf2f(unsigned short b) {
    union { unsigned u; float f; } v; v.u = ((unsigned)b) << 16;
    return v.f;
}
static __device__ __forceinline__ s16x8 pack8(f32x4 a, f32x4 b) {
    s16x8 r;
    r[0] = (short)f2bf(a[0]); r[1] = (short)f2bf(a[1]);
    r[2] = (short)f2bf(a[2]); r[3] = (short)f2bf(a[3]);
    r[4] = (short)f2bf(b[0]); r[5] = (short)f2bf(b[1]);
    r[6] = (short)f2bf(b[2]); r[7] = (short)f2bf(b[3]);
    return r;
}
static __device__ __forceinline__ void split8(f32x4 a, f32x4 b, s16x8* hi, s16x8* lo) {
    s16x8 h, l;
#pragma unroll
    for (int e = 0; e < 4; e++) {
        unsigned short hh = f2bf(a[e]); h[e] = (short)hh;
        l[e] = (short)f2bf(a[e] - bf2f(hh));
    }
#pragma unroll
    for (int e = 0; e < 4; e++) {
        unsigned short hh = f2bf(b[e]); h[4 + e] = (short)hh;
        l[4 + e] = (short)f2bf(b[e] - bf2f(hh));
    }
    *hi = h; *lo = l;
}
static __device__ __forceinline__ f32x4 mfma16(s16x8 a, s16x8 b, f32x4 c) {
    return __builtin_amdgcn_mfma_f32_16x16x32_bf16(a, b, c, 0, 0, 0);
}

// ---- agent-scope (sc1/MALL) primitives — proven in r2-r6 ----
static __device__ __forceinline__ unsigned ld_agent(const unsigned* p) {
    return __hip_atomic_load(p, __ATOMIC_RELAXED, __HIP_MEMORY_SCOPE_AGENT);
}
static __device__ __forceinline__ void add_agent(unsigned* p, unsigned v) {
    __hip_atomic_fetch_add(p, v, __ATOMIC_RELAXED, __HIP_MEMORY_SCOPE_AGENT);
}
static __device__ __forceinline__ void st_agent(unsigned* p, unsigned v) {
    __hip_atomic_store(p, v, __ATOMIC_RELAXED, __HIP_MEMORY_SCOPE_AGENT);
}
static __device__ __forceinline__ void poll_agent_ge(unsigned* p, unsigned tgt) {
    while (ld_agent(p) < tgt) __builtin_amdgcn_s_sleep(4);
}
static __device__ __forceinline__ void vm_drain() {
    asm volatile("s_waitcnt vmcnt(0)" ::: "memory");
}

// ---- L2-point primitives (no sc1: stay within issuing XCD's L2) ----
static __device__ __forceinline__ void atomic_add_l2(unsigned int* p, unsigned v) {
    asm volatile("global_atomic_add %0, %1, off" :: "v"(p), "v"(v) : "memory");
}
static __device__ __forceinline__ unsigned ld_u32_sc0_wait(const unsigned int* p) {
    unsigned v;
    asm volatile("global_load_dword %0, %1, off sc0\n\ts_waitcnt vmcnt(0)"
                 : "=v"(v) : "v"(p) : "memory");
    return v;
}
static __device__ __forceinline__ unsigned ld_plain_wait(const unsigned int* p) {
    unsigned v;
    asm volatile("global_load_dword %0, %1, off\n\ts_waitcnt vmcnt(0)"
                 : "=v"(v) : "v"(p) : "memory");
    return v;
}
static __device__ __forceinline__ void st_plain(unsigned int* p, unsigned v) {
    asm volatile("global_store_dword %0, %1, off" :: "v"(p), "v"(v) : "memory");
}

// ---------------------------------------------------------------------------
// GEMM (unchanged, proven)
// ---------------------------------------------------------------------------
template<int SPLIT, int TANH, int BIAS, int AIN, int OUTBF16>
__global__ __launch_bounds__(256, 2)
void gemm_k(const void* __restrict__ Ap, const float* __restrict__ Wp,
            const float* __restrict__ bias, void* __restrict__ outp,
            int M, int N)
{
    const int bm = blockIdx.x, bn = blockIdx.y;
    const int tid = threadIdx.x;
    const int w = tid >> 6, lane = tid & 63;
    const int l15 = lane & 15, l4 = lane >> 4;

    __shared__ unsigned short Al[128 * 72 * (SPLIT ? 2 : 1)];
    __shared__ unsigned short Wl[128 * 72 * (SPLIT ? 2 : 1)];
    const int LOFS = 128 * 72;

    f32x4 acc[4][4];
#pragma unroll
    for (int i = 0; i < 4; i++)
#pragma unroll
        for (int j = 0; j < 4; j++) acc[i][j] = (f32x4){0.f, 0.f, 0.f, 0.f};

    const int srow = tid >> 1, shalf = tid & 1;
    const float* Asrc = (const float*)Ap + (size_t)(bm * 128 + srow) * 512 + shalf * 32;
    const unsigned short* Asrcb = (const unsigned short*)Ap + (size_t)(bm * 128 + srow) * 512 + shalf * 32;
    const float* Wsrc = Wp + (size_t)(bn * 128 + srow) * 512 + shalf * 32;
    unsigned short* Adst = Al + srow * 72 + shalf * 32;
    unsigned short* Wdst = Wl + srow * 72 + shalf * 32;

    for (int k0 = 0; k0 < 512; k0 += 64) {
        __syncthreads();
        if (AIN) {
#pragma unroll
            for (int j = 0; j < 4; j++)
                *(s16x8*)(Adst + j * 8) = *(const s16x8*)(Asrcb + k0 + j * 8);
        } else if (SPLIT) {
#pragma unroll
            for (int j = 0; j < 4; j++) {
                f32x4 x = *(const f32x4*)(Asrc + k0 + j * 8);
                f32x4 y = *(const f32x4*)(Asrc + k0 + j * 8 + 4);
                s16x8 hi, lo; split8(x, y, &hi, &lo);
                *(s16x8*)(Adst + j * 8) = hi;
                *(s16x8*)(Adst + LOFS + j * 8) = lo;
            }
        } else {
#pragma unroll
            for (int j = 0; j < 4; j++) {
                f32x4 x = *(const f32x4*)(Asrc + k0 + j * 8);
                f32x4 y = *(const f32x4*)(Asrc + k0 + j * 8 + 4);
                *(s16x8*)(Adst + j * 8) = pack8(x, y);
            }
        }
        if (SPLIT) {
#pragma unroll
            for (int j = 0; j < 4; j++) {
                f32x4 x = *(const f32x4*)(Wsrc + k0 + j * 8);
                f32x4 y = *(const f32x4*)(Wsrc + k0 + j * 8 + 4);
                s16x8 hi, lo; split8(x, y, &hi, &lo);
                *(s16x8*)(Wdst + j * 8) = hi;
                *(s16x8*)(Wdst + LOFS + j * 8) = lo;
            }
        } else {
#pragma unroll
            for (int j = 0; j < 4; j++) {
                f32x4 x = *(const f32x4*)(Wsrc + k0 + j * 8);
                f32x4 y = *(const f32x4*)(Wsrc + k0 + j * 8 + 4);
                *(s16x8*)(Wdst + j * 8) = pack8(x, y);
            }
        }
        __syncthreads();

#pragma unroll
        for (int kt = 0; kt < 2; kt++) {
            s16x8 afh[4], bfh[4];
#pragma unroll
            for (int mb = 0; mb < 4; mb++)
                afh[mb] = *(const s16x8*)(Al + ((w & 1) * 64 + mb * 16 + l15) * 72 + kt * 32 + l4 * 8);
#pragma unroll
            for (int nb = 0; nb < 4; nb++)
                bfh[nb] = *(const s16x8*)(Wl + ((w >> 1) * 64 + nb * 16 + l15) * 72 + kt * 32 + l4 * 8);
            if (SPLIT) {
                s16x8 afl[4], bfl[4];
#pragma unroll
                for (int mb = 0; mb < 4; mb++)
                    afl[mb] = *(const s16x8*)(Al + LOFS + ((w & 1) * 64 + mb * 16 + l15) * 72 + kt * 32 + l4 * 8);
#pragma unroll
                for (int nb = 0; nb < 4; nb++)
                    bfl[nb] = *(const s16x8*)(Wl + LOFS + ((w >> 1) * 64 + nb * 16 + l15) * 72 + kt * 32 + l4 * 8);
#pragma unroll
                for (int mb = 0; mb < 4; mb++)
#pragma unroll
                    for (int nb = 0; nb < 4; nb++) {
                        acc[mb][nb] = mfma16(afh[mb], bfh[nb], acc[mb][nb]);
                        acc[mb][nb] = mfma16(afh[mb], bfl[nb], acc[mb][nb]);
                        acc[mb][nb] = mfma16(afl[mb], bfh[nb], acc[mb][nb]);
                    }
            } else {
#pragma unroll
                for (int mb = 0; mb < 4; mb++)
#pragma unroll
                    for (int nb = 0; nb < 4; nb++)
                        acc[mb][nb] = mfma16(afh[mb], bfh[nb], acc[mb][nb]);
            }
        }
    }

    const int m0 = bm * 128 + (w & 1) * 64;
    const int n0 = bn * 128 + (w >> 1) * 64;
#pragma unroll
    for (int nb = 0; nb < 4; nb++) {
        float bv = 0.0f;
        const int n = n0 + nb * 16 + l15;
        if (BIAS) bv = bias[n];
#pragma unroll
        for (int mb = 0; mb < 4; mb++) {
#pragma unroll
            for (int i = 0; i < 4; i++) {
                const int m = m0 + mb * 16 + l4 * 4 + i;
                float vv = acc[mb][nb][i];
                if (BIAS) vv += bv;
                if (TANH) vv = tanh_fast(vv);
                if (OUTBF16) ((unsigned short*)outp)[(size_t)m * N + n] = f2bf(vv);
                else        ((float*)outp)[(size_t)m * N + n] = vv;
            }
        }
    }
}

// ---------------------------------------------------------------------------
// Fused attention (unchanged, proven)
// ---------------------------------------------------------------------------
__global__ __launch_bounds__(512, 4)
void att_k(const float* __restrict__ Pt, const float* __restrict__ Qt,
           const float* __restrict__ Vv, const float* __restrict__ vin,
           unsigned short* __restrict__ cbuf)
{
    const int tblk = blockIdx.x, b = blockIdx.y;
    const int tid = threadIdx.x;
    const int w = tid >> 6, lane = tid & 63;
    const int t_in = lane >> 5, sl = lane & 31;
    const int t_loc = w * 2 + t_in;
    const int tg = tblk * 16 + t_loc;

    __shared__ float sbuf[16][513];
    __shared__ float qst[8][640];
    __shared__ float zinv[16];

    float Pa[16], Vb[16], VbA[16];
    {
        const float* pp = Pt + ((size_t)tg * 64 + b) * 512 + sl * 16;
        const float* vb = Vv + (size_t)b * 512 + sl * 16;
#pragma unroll
        for (int j = 0; j < 4; j++) {
            f32x4 x = *(const f32x4*)(pp + j * 4);
            f32x4 y = *(const f32x4*)(vb + j * 4);
#pragma unroll
            for (int e = 0; e < 4; e++) { Pa[j * 4 + e] = x[e]; Vb[j * 4 + e] = y[e]; }
        }
#pragma unroll
        for (int e = 0; e < 16; e++) VbA[e] = Vb[e] * Pa[e];
    }

    for (int l0 = 0; l0 < 512; l0 += 8) {
        __syncthreads();
        {
            const int row = tid >> 6;
            const int cb = (tid & 63) * 8;
            const float* src = Qt + ((size_t)(l0 + row) * 64 + b) * 512 + cb;
            const int f0 = cb + 4 * (cb >> 4);
            *(f32x4*)(&qst[row][f0])     = *(const f32x4*)(src);
            *(f32x4*)(&qst[row][f0 + 4]) = *(const f32x4*)(src + 4);
        }
        __syncthreads();
        for (int l = 0; l < 8; l++) {
            const float* qrow = &qst[l][sl * 20];
            float a0 = 0.f, a1 = 0.f, a2 = 0.f, a3 = 0.f;
#pragma unroll
            for (int j = 0; j < 4; j++) {
                f32x4 q = *(const f32x4*)(qrow + j * 4);
                {
                    float d = fmaf(Pa[4 * j + 0], q[0], 1.0f);
                    a0 = fmaf(fmaf(Vb[4 * j + 0], q[0], VbA[4 * j + 0]), rcp_fast(d), a0);
                }
                {
                    float d = fmaf(Pa[4 * j + 1], q[1], 1.0f);
                    a1 = fmaf(fmaf(Vb[4 * j + 1], q[1], VbA[4 * j + 1]), rcp_fast(d), a1);
                }
                {
                    float d = fmaf(Pa[4 * j + 2], q[2], 1.0f);
                    a2 = fmaf(fmaf(Vb[4 * j + 2], q[2], VbA[4 * j + 2]), rcp_fast(d), a2);
                }
                {
                    float d = fmaf(Pa[4 * j + 3], q[3], 1.0f);
                    a3 = fmaf(fmaf(Vb[4 * j + 3], q[3], VbA[4 * j + 3]), rcp_fast(d), a3);
                }
            }
            float accp = (a0 + a1) + (a2 + a3);
#pragma unroll
            for (int m = 1; m < 32; m <<= 1) accp += __shfl_xor(accp, m, 64);
            if (sl == 0) sbuf[t_loc][l0 + l] = accp;
        }
    }
    __syncthreads();

    {
        const int tr = tid >> 5;
        const int i = tid & 31;
        float m = -1e30f;
        for (int l = i; l < 512; l += 32) m = fmaxf(m, sbuf[tr][l]);
#pragma unroll
        for (int mm = 1; mm < 32; mm <<= 1) m = fmaxf(m, __shfl_xor(m, mm, 64));
        float z = 0.0f;
        for (int l = i; l < 512; l += 32) {
            float e = __expf(sbuf[tr][l] - m);
            sbuf[tr][l] = e;
            z += e;
        }
#pragma unroll
        for (int mm = 1; mm < 32; mm <<= 1) z += __shfl_xor(z, mm, 64);
        if (i == 0) zinv[tr] = rcp_fast(z);
    }
    __syncthreads();

    float ca[16];
#pragma unroll
    for (int j = 0; j < 16; j++) ca[j] = 0.0f;

    for (int l0 = 0; l0 < 512; l0 += 8) {
        __syncthreads();
        {
            const int row = tid >> 6;
            const int cb = (tid & 63) * 8;
            const float* src = vin + ((size_t)(l0 + row) * 64 + b) * 512 + cb;
            const int f0 = cb + 4 * (cb >> 4);
            *(f32x4*)(&qst[row][f0])     = *(const f32x4*)(src);
            *(f32x4*)(&qst[row][f0 + 4]) = *(const f32x4*)(src + 4);
        }
        __syncthreads();
        for (int l = 0; l < 8; l++) {
            const float a = sbuf[t_loc][l0 + l];
            const float* vrow = &qst[l][sl * 20];
#pragma unroll
            for (int j = 0; j < 4; j++) {
                f32x4 x = *(const f32x4*)(vrow + j * 4);
                ca[4 * j + 0] = fmaf(a, x[0], ca[4 * j + 0]);
                ca[4 * j + 1] = fmaf(a, x[1], ca[4 * j + 1]);
                ca[4 * j + 2] = fmaf(a, x[2], ca[4 * j + 2]);
                ca[4 * j + 3] = fmaf(a, x[3], ca[4 * j + 3]);
            }
        }
    }
    const float zi = zinv[t_loc];
    unsigned short* co = cbuf + ((size_t)tg * 64 + b) * 512 + sl * 16;
#pragma unroll
    for (int j = 0; j < 4; j++) {
        s16x4 o;
        o[0] = (short)f2bf(ca[4 * j + 0] * zi);
        o[1] = (short)f2bf(ca[4 * j + 1] * zi);
        o[2] = (short)f2bf(ca[4 * j + 2] * zi);
        o[3] = (short)f2bf(ca[4 * j + 3] * zi);
        *(s16x4*)(co + j * 4) = o;
    }
}

// ---------------------------------------------------------------------------
// rec_k v5. ctrl u32 offsets (as r6):
//   barA [0,4096) | xarr [4096,4160) | acnt 4160 | rdy/tflg/vote/done
//   4176/4192/4208/4224 (+8 each) | test 4352+g*32 | barL2 [4608,8704)
// ---------------------------------------------------------------------------
#define C_BAR   0
#define C_XARR  4096
#define C_ACNT  4160
#define C_RDY   4176
#define C_TFLG  4192
#define C_VOTE  4208
#define C_DONE  4224
#define C_TEST  4352
#define C_BARL2 4608
#define MAGIC   0x5A5AA5A5u
#define HWREG_XCC_ID (20 | (31 << 11))

__global__ __launch_bounds__(256, 1)
void rec_k(const unsigned short* __restrict__ Gi,
           const float* __restrict__ Whh, const float* __restrict__ bhh,
           const float* __restrict__ h0,
           unsigned int* __restrict__ hb32,
           unsigned int* __restrict__ ctrl,
           float* __restrict__ hs)
{
    const int tid = threadIdx.x;
    const int bid = blockIdx.x;
    __shared__ int sh_g, sh_sub, sh_fast;
    __shared__ unsigned sh_xv[64];

    // ---------- deterministic grouping + probe (r6-proven; all polls guaranteed) ----------
    if (tid == 0) {
        const unsigned xcd = ((unsigned)__builtin_amdgcn_s_getreg(HWREG_XCC_ID)) & 7u;
        unsigned* xarr = ctrl + C_XARR;
        unsigned* acnt = ctrl + C_ACNT;
        st_agent(&xarr[bid], 0x100u | xcd);
        vm_drain();
        add_agent(acnt, 1u);
        poll_agent_ge(acnt, 64u);
        for (int i = 0; i < 64; i++) sh_xv[i] = ld_agent(&xarr[i]) & 7u;

        int rank = 0;
        for (int i = 0; i < 64; i++)
            if (sh_xv[i] < xcd || (sh_xv[i] == xcd && i < bid)) rank++;
        const int g = rank >> 3, sub = rank & 7;

        int uni = 1;
        {
            unsigned gx = 0xFFu;
            for (int i = 0; i < 64; i++) {
                int ri = 0;
                for (int j = 0; j < 64; j++)
                    if (sh_xv[j] < sh_xv[i] || (sh_xv[j] == sh_xv[i] && j < i)) ri++;
                if ((ri >> 3) == g) {
                    if (gx == 0xFFu) gx = sh_xv[i];
                    else if (sh_xv[i] != gx) uni = 0;
                }
            }
        }

        unsigned* rdy  = ctrl + C_RDY;
        unsigned* tflg = ctrl + C_TFLG;
        unsigned* vote = ctrl + C_VOTE;
        unsigned* done = ctrl + C_DONE;
        unsigned* test = ctrl + C_TEST + g * 32;
        unsigned saw;
        if (sub != 0) {
            unsigned pr = ld_plain_wait(test);
            asm volatile("" :: "v"(pr));
            add_agent(&rdy[g], 1u);
            poll_agent_ge(&tflg[g], 1u);
            unsigned u = ld_u32_sc0_wait(test);
            saw = (u == MAGIC) ? 1u : 0u;
        } else {
            poll_agent_ge(&rdy[g], 7u);
            st_plain(test, MAGIC);
            vm_drain();
            add_agent(&tflg[g], 1u);
            saw = 1u;
        }
        add_agent(&vote[g], saw);
        vm_drain();
        add_agent(&done[g], 1u);
        poll_agent_ge(&done[g], 8u);
        sh_fast = (uni && ld_agent(&vote[g]) == 8u) ? 1 : 0;
        sh_g = g; sh_sub = sub;
    }
    __syncthreads();
    const int g = sh_g, sub = sh_sub;
    int fast = sh_fast;

    // ---------- geometry ----------
    const int w = tid >> 6;
    const int lane = tid & 63;
    const int l15 = lane & 15, l4 = lane >> 4;
    const int b  = g * 8 + (l15 & 7);
    const int jb = sub * 64 + w * 16;
    const int jrow = l4 * 4;
    const bool writer = (l15 < 8);

    s16x8 wf[3][16];
#pragma unroll
    for (int gg = 0; gg < 3; gg++) {
        const float* wr = Whh + (size_t)(gg * 512 + jb + l15) * 512 + l4 * 8;
#pragma unroll
        for (int c = 0; c < 16; c++) {
            f32x4 x = *(const f32x4*)(wr + c * 32);
            f32x4 y = *(const f32x4*)(wr + c * 32 + 4);
            wf[gg][c] = pack8(x, y);
        }
    }

    float bh_r[4], bh_z[4], bh_n[4];
#pragma unroll
    for (int i = 0; i < 4; i++) {
        bh_r[i] = bhh[jb + jrow + i];
        bh_z[i] = bhh[512 + jb + jrow + i];
        bh_n[i] = bhh[1024 + jb + jrow + i];
    }
    float hp[4];
#pragma unroll
    for (int i = 0; i < 4; i++) hp[i] = h0[(size_t)b * 512 + jb + jrow + i];

    unsigned* barA  = ctrl + C_BAR   + g * 512;
    unsigned* barL2 = ctrl + C_BARL2 + g * 512;

    s16x4 g0, g1, g2;
    {
        const unsigned short* gp = Gi + (size_t)b * 1536 + jb + jrow;
        g0 = *(const s16x4*)(gp);
        g1 = *(const s16x4*)(gp + 512);
        g2 = *(const s16x4*)(gp + 1024);
    }

#define LDH(i, lit) asm volatile("global_load_dwordx4 %0, %1, off offset:" lit " sc0" \
                                 : "=v"(hfrag[i]) : "v"(src) : "memory");

    for (int t = 0; t < 512; t++) {
        s16x8 hfrag[16];
        if (t == 0) {
            const float* hr = h0 + (size_t)b * 512 + l4 * 8;
#pragma unroll
            for (int c = 0; c < 16; c++) {
                f32x4 x = *(const f32x4*)(hr + c * 32);
                f32x4 y = *(const f32x4*)(hr + c * 32 + 4);
                hfrag[c] = pack8(x, y);
            }
        } else if (fast) {
            const unsigned int* src = hb32 + (t & 1) * 16384 + b * 256 + l4 * 4;
            LDH(0, "0")   LDH(1, "64")  LDH(2, "128")  LDH(3, "192")
            LDH(4, "256") LDH(5, "320") LDH(6, "384")  LDH(7, "448")
            LDH(8, "512") LDH(9, "576") LDH(10, "640") LDH(11, "704")
            LDH(12, "768") LDH(13, "832") LDH(14, "896") LDH(15, "960")
            vm_drain();
            __builtin_amdgcn_sched_barrier(0);
        } else {
            const unsigned int* src = hb32 + (t & 1) * 16384 + b * 256 + l4 * 4;
#pragma unroll
            for (int c = 0; c < 16; c++) {
                union { unsigned int u[4]; s16x8 v; } cv;
#pragma unroll
                for (int q = 0; q < 4; q++)
                    cv.u[q] = ld_agent(src + c * 16 + q);
                hfrag[c] = cv.v;
            }
        }

        f32x4 acc0 = {0.f, 0.f, 0.f, 0.f};
        f32x4 acc1 = {0.f, 0.f, 0.f, 0.f};
        f32x4 acc2 = {0.f, 0.f, 0.f, 0.f};
#pragma unroll
        for (int c = 0; c < 16; c++) {
            acc0 = mfma16(wf[0][c], hfrag[c], acc0);
            acc1 = mfma16(wf[1][c], hfrag[c], acc1);
            acc2 = mfma16(wf[2][c], hfrag[c], acc2);
        }

#pragma unroll
        for (int i = 0; i < 4; i++) {
            float rr = sigmoid_fast(bf2f((unsigned short)g0[i]) + acc0[i] + bh_r[i]);
            float zz = sigmoid_fast(bf2f((unsigned short)g1[i]) + acc1[i] + bh_z[i]);
            float nn = tanh_fast(bf2f((unsigned short)g2[i]) + rr * (acc2[i] + bh_n[i]));
            hp[i] = fmaf(zz, hp[i] - nn, nn);
        }

        float* hso = hs + ((size_t)t * 64 + b) * 512 + jb + jrow;

        if (t < 511) {
            const unsigned p0 = (unsigned)f2bf(hp[0]) | ((unsigned)f2bf(hp[1]) << 16);
            const unsigned p1 = (unsigned)f2bf(hp[2]) | ((unsigned)f2bf(hp[3]) << 16);
            unsigned int* dst = hb32 + ((t + 1) & 1) * 16384 + b * 256 + ((jb + jrow) >> 1);
            if (writer) {
                if (fast) { u32x2 pp = {p0, p1}; *(u32x2*)dst = pp; }
                else { st_agent(dst, p0); st_agent(dst + 1, p1); }
            }
            vm_drain();                               // own wave's h stores ACKed in L2
            if (lane == 0) {
                if (fast) atomic_add_l2(barL2 + t, 1u);
                else      add_agent(barA + t, 1u);
            }

            // hide under the wait: hs store + Gi prefetch
            if (writer) {
                f32x4 hv = {hp[0], hp[1], hp[2], hp[3]};
                __builtin_nontemporal_store(hv, (f32x4*)hso);
            }
            s16x4 n0, n1, n2;
            {
                const unsigned short* gp = Gi + ((size_t)(t + 1) * 64 + b) * 1536 + jb + jrow;
                n0 = *(const s16x4*)(gp);
                n1 = *(const s16x4*)(gp + 512);
                n2 = *(const s16x4*)(gp + 1024);
            }

            // wave-autonomous poll (no syncthreads, no RMW, no sleep)
            if (fast) {
                bool ok = false;
                unsigned it = 0;
                for (;;) {
                    unsigned v = 0;
                    if (lane == 0) v = ld_u32_sc0_wait(barL2 + t);
                    v = (unsigned)__shfl((int)v, 0, 64);
                    if (v >= 32u) { ok = true; break; }
                    if (++it >= 4096u) break;         // watchdog
                }
                if (!ok) {
                    // demote round: republish agent-scope, add agent flag, poll both.
                    // A split group can never bring one L2 copy to 32 -> all waves
                    // land here and exit via barA (uniform slow); a healthy group
                    // always reaches 32 on barL2 (fast exit, fast stays 1).
                    if (writer) { st_agent(dst, p0); st_agent(dst + 1, p1); }
                    vm_drain();
                    if (lane == 0) add_agent(barA + t, 1u);
                    for (;;) {
                        unsigned v1 = 0, v2 = 0;
                        if (lane == 0) {
                            v1 = ld_u32_sc0_wait(barL2 + t);
                            v2 = ld_agent(barA + t);
                        }
                        v1 = (unsigned)__shfl((int)v1, 0, 64);
                        v2 = (unsigned)__shfl((int)v2, 0, 64);
                        if (v1 >= 32u) break;                       // fast after all
                        if (v2 >= 32u) { fast = 0; break; }         // permanent demote
                        __builtin_amdgcn_s_sleep(2);
                    }
                }
            } else {
                for (;;) {
                    unsigned v = 0;
                    if (lane == 0) v = ld_agent(barA + t);
                    v = (unsigned)__shfl((int)v, 0, 64);
                    if (v >= 32u) break;
                    __builtin_amdgcn_s_sleep(1);
                }
            }
            g0 = n0; g1 = n1; g2 = n2;
        } else {
            if (writer) {
                f32x4 hv = {hp[0], hp[1], hp[2], hp[3]};
                *(f32x4*)hso = hv;
            }
        }
    }
#undef LDH
}

// ---------------------------------------------------------------------------
// ws layout (bytes):
//   Pt  : [0, 64Mi)        f32   Qt: [64Mi,128Mi)   c: [128Mi,160Mi) bf16
//   Gi  : [0, 96Mi)        bf16 (overlays Pt/Qt, dead by then)
//   hb32: [160Mi, +128Ki)  u32 bf16-pairs
//   ctrl: [160Mi+128Ki, +34816B)
// ---------------------------------------------------------------------------
extern "C" void kernel_launch(void* const* d_in, const int* in_sizes, int n_in,
                              void* d_out, int out_size, void* d_ws, size_t ws_size,
                              hipStream_t stream)
{
    (void)in_sizes; (void)n_in; (void)out_size; (void)ws_size;
    const float* v   = (const float*)d_in[0];
    const float* h0  = (const float*)d_in[1];
    const float* Vv  = (const float*)d_in[2];
    const float* Wp  = (const float*)d_in[3];
    const float* Wp_ = (const float*)d_in[4];
    const float* Wih = (const float*)d_in[5];
    const float* Whh = (const float*)d_in[6];
    const float* bih = (const float*)d_in[7];
    const float* bhh = (const float*)d_in[8];
    float* hs = (float*)d_out;

    char* ws = (char*)d_ws;
    float* Pt = (float*)(ws);
    float* Qt = (float*)(ws + 67108864ULL);
    unsigned short* cb  = (unsigned short*)(ws + 134217728ULL);
    unsigned short* Gi  = (unsigned short*)(ws);
    unsigned int*   hb32 = (unsigned int*)(ws + 167772160ULL);
    unsigned int*   ctrl = (unsigned int*)(ws + 167772160ULL + 131072ULL);

    hipMemsetAsync(ctrl, 0, 8704 * sizeof(unsigned int), stream);

    dim3 gpq(256, 4, 1);
    gemm_k<1, 1, 0, 0, 0><<<gpq, 256, 0, stream>>>(v, Wp, nullptr, Pt, 32768, 512);
    gemm_k<1, 1, 0, 0, 0><<<gpq, 256, 0, stream>>>(v, Wp_, nullptr, Qt, 32768, 512);

    att_k<<<dim3(32, 64), 512, 0, stream>>>(Pt, Qt, Vv, v, cb);

    gemm_k<0, 0, 1, 1, 1><<<dim3(256, 12), 256, 0, stream>>>(cb, Wih, bih, Gi, 32768, 1536);

    rec_k<<<dim3(64), 256, 0, stream>>>(Gi, Whh, bhh, h0, hb32, ctrl, hs);
}

// Round 8
// 5135.657 us; speedup vs baseline: 1.1015x; 1.1015x over previous
//
#include <hip/hip_runtime.h>
#include <hip/hip_bf16.h>

// L=512, B=64, D=H=512, 3H=1536.
//  gemm_k<SPLIT,TANH>: Pt/Qt = tanh(v@Wp^T)  (split-bf16 3-pass MFMA)
//  att_k: logits via tanh addition formula, softmax, c = a·v  (c bf16)
//  gemm_k<AIN,BIAS,OUTBF16>: Gi = c@W_ih^T + b_ih
//  rec_k v6: r6 skeleton (64 blocks, XCD grouping, 8 groups x 8 blocks x 4 waves,
//    block-level flag adds after one __syncthreads) with three fixes:
//    (1) polls = plain sc0 LOADS (no RMW serialization) + sleep throttle,
//    (2) hs stores PLAIN (L2 ack ~200cy; r6's nontemporal parked an HBM ack
//        inside every later vmcnt(0)),
//    (3) no second barrier: waves poll independently and proceed on count==8
//        (safe: count==8 implies all waves passed bar1, so all reads of the
//        buffer overwritten next step are done). Watchdog+demote kept.

typedef float f32x4 __attribute__((ext_vector_type(4)));
typedef short s16x8 __attribute__((ext_vector_type(8)));
typedef short s16x4 __attribute__((ext_vector_type(4)));
typedef unsigned int u32x2 __attribute__((ext_vector_type(2)));

static __device__ __forceinline__ float rcp_fast(float x) { return __builtin_amdgcn_rcpf(x); }
static __device__ __forceinline__ float tanh_fast(float x) {
    float e = __expf(2.0f * x);
    return 1.0f - 2.0f * rcp_fast(e + 1.0f);
}
static __device__ __forceinline__ float sigmoid_fast(float x) {
    return rcp_fast(1.0f + __expf(-x));
}
static __device__ __forceinline__ unsigned short f2bf(float x) {
    union { float f; unsigned u; } v; v.f = x;
    unsigned r = v.u + 0x7FFFu + ((v.u >> 16) & 1u);
    return (unsigned short)(r >> 16);
}
static __device__ __forceinline__ float bf2f(unsigned short b) {
    union { unsigned u; float f; } v; v.u = ((unsigned)b) << 16;
    return v.f;
}
static __device__ __forceinline__ s16x8 pack8(f32x4 a, f32x4 b) {
    s16x8 r;
    r[0] = (short)f2bf(a[0]); r[1] = (short)f2bf(a[1]);
    r[2] = (short)f2bf(a[2]); r[3] = (short)f2bf(a[3]);
    r[4] = (short)f2bf(b[0]); r[5] = (short)f2bf(b[1]);
    r[6] = (short)f2bf(b[2]); r[7] = (short)f2bf(b[3]);
    return r;
}
static __device__ __forceinline__ void split8(f32x4 a, f32x4 b, s16x8* hi, s16x8* lo) {
    s16x8 h, l;
#pragma unroll
    for (int e = 0; e < 4; e++) {
        unsigned short hh = f2bf(a[e]); h[e] = (short)hh;
        l[e] = (short)f2bf(a[e] - bf2f(hh));
    }
#pragma unroll
    for (int e = 0; e < 4; e++) {
        unsigned short hh = f2bf(b[e]); h[4 + e] = (short)hh;
        l[4 + e] = (short)f2bf(b[e] - bf2f(hh));
    }
    *hi = h; *lo = l;
}
static __device__ __forceinline__ f32x4 mfma16(s16x8 a, s16x8 b, f32x4 c) {
    return __builtin_amdgcn_mfma_f32_16x16x32_bf16(a, b, c, 0, 0, 0);
}

// ---- agent-scope (sc1/MALL) primitives — proven r2-r7 ----
static __device__ __forceinline__ unsigned ld_agent(const unsigned* p) {
    return __hip_atomic_load(p, __ATOMIC_RELAXED, __HIP_MEMORY_SCOPE_AGENT);
}
static __device__ __forceinline__ void add_agent(unsigned* p, unsigned v) {
    __hip_atomic_fetch_add(p, v, __ATOMIC_RELAXED, __HIP_MEMORY_SCOPE_AGENT);
}
static __device__ __forceinline__ void st_agent(unsigned* p, unsigned v) {
    __hip_atomic_store(p, v, __ATOMIC_RELAXED, __HIP_MEMORY_SCOPE_AGENT);
}
static __device__ __forceinline__ void poll_agent_ge(unsigned* p, unsigned tgt) {
    while (ld_agent(p) < tgt) __builtin_amdgcn_s_sleep(4);
}
static __device__ __forceinline__ void vm_drain() {
    asm volatile("s_waitcnt vmcnt(0)" ::: "memory");
}

// ---- L2-point primitives (no sc1: stay within issuing XCD's L2) ----
static __device__ __forceinline__ void atomic_add_l2(unsigned int* p, unsigned v) {
    asm volatile("global_atomic_add %0, %1, off" :: "v"(p), "v"(v) : "memory");
}
static __device__ __forceinline__ unsigned ld_u32_sc0_wait(const unsigned int* p) {
    unsigned v;
    asm volatile("global_load_dword %0, %1, off sc0\n\ts_waitcnt vmcnt(0)"
                 : "=v"(v) : "v"(p) : "memory");
    return v;
}
static __device__ __forceinline__ unsigned ld_plain_wait(const unsigned int* p) {
    unsigned v;
    asm volatile("global_load_dword %0, %1, off\n\ts_waitcnt vmcnt(0)"
                 : "=v"(v) : "v"(p) : "memory");
    return v;
}
static __device__ __forceinline__ void st_plain(unsigned int* p, unsigned v) {
    asm volatile("global_store_dword %0, %1, off" :: "v"(p), "v"(v) : "memory");
}

// ---------------------------------------------------------------------------
// GEMM (unchanged, proven)
// ---------------------------------------------------------------------------
template<int SPLIT, int TANH, int BIAS, int AIN, int OUTBF16>
__global__ __launch_bounds__(256, 2)
void gemm_k(const void* __restrict__ Ap, const float* __restrict__ Wp,
            const float* __restrict__ bias, void* __restrict__ outp,
            int M, int N)
{
    const int bm = blockIdx.x, bn = blockIdx.y;
    const int tid = threadIdx.x;
    const int w = tid >> 6, lane = tid & 63;
    const int l15 = lane & 15, l4 = lane >> 4;

    __shared__ unsigned short Al[128 * 72 * (SPLIT ? 2 : 1)];
    __shared__ unsigned short Wl[128 * 72 * (SPLIT ? 2 : 1)];
    const int LOFS = 128 * 72;

    f32x4 acc[4][4];
#pragma unroll
    for (int i = 0; i < 4; i++)
#pragma unroll
        for (int j = 0; j < 4; j++) acc[i][j] = (f32x4){0.f, 0.f, 0.f, 0.f};

    const int srow = tid >> 1, shalf = tid & 1;
    const float* Asrc = (const float*)Ap + (size_t)(bm * 128 + srow) * 512 + shalf * 32;
    const unsigned short* Asrcb = (const unsigned short*)Ap + (size_t)(bm * 128 + srow) * 512 + shalf * 32;
    const float* Wsrc = Wp + (size_t)(bn * 128 + srow) * 512 + shalf * 32;
    unsigned short* Adst = Al + srow * 72 + shalf * 32;
    unsigned short* Wdst = Wl + srow * 72 + shalf * 32;

    for (int k0 = 0; k0 < 512; k0 += 64) {
        __syncthreads();
        if (AIN) {
#pragma unroll
            for (int j = 0; j < 4; j++)
                *(s16x8*)(Adst + j * 8) = *(const s16x8*)(Asrcb + k0 + j * 8);
        } else if (SPLIT) {
#pragma unroll
            for (int j = 0; j < 4; j++) {
                f32x4 x = *(const f32x4*)(Asrc + k0 + j * 8);
                f32x4 y = *(const f32x4*)(Asrc + k0 + j * 8 + 4);
                s16x8 hi, lo; split8(x, y, &hi, &lo);
                *(s16x8*)(Adst + j * 8) = hi;
                *(s16x8*)(Adst + LOFS + j * 8) = lo;
            }
        } else {
#pragma unroll
            for (int j = 0; j < 4; j++) {
                f32x4 x = *(const f32x4*)(Asrc + k0 + j * 8);
                f32x4 y = *(const f32x4*)(Asrc + k0 + j * 8 + 4);
                *(s16x8*)(Adst + j * 8) = pack8(x, y);
            }
        }
        if (SPLIT) {
#pragma unroll
            for (int j = 0; j < 4; j++) {
                f32x4 x = *(const f32x4*)(Wsrc + k0 + j * 8);
                f32x4 y = *(const f32x4*)(Wsrc + k0 + j * 8 + 4);
                s16x8 hi, lo; split8(x, y, &hi, &lo);
                *(s16x8*)(Wdst + j * 8) = hi;
                *(s16x8*)(Wdst + LOFS + j * 8) = lo;
            }
        } else {
#pragma unroll
            for (int j = 0; j < 4; j++) {
                f32x4 x = *(const f32x4*)(Wsrc + k0 + j * 8);
                f32x4 y = *(const f32x4*)(Wsrc + k0 + j * 8 + 4);
                *(s16x8*)(Wdst + j * 8) = pack8(x, y);
            }
        }
        __syncthreads();

#pragma unroll
        for (int kt = 0; kt < 2; kt++) {
            s16x8 afh[4], bfh[4];
#pragma unroll
            for (int mb = 0; mb < 4; mb++)
                afh[mb] = *(const s16x8*)(Al + ((w & 1) * 64 + mb * 16 + l15) * 72 + kt * 32 + l4 * 8);
#pragma unroll
            for (int nb = 0; nb < 4; nb++)
                bfh[nb] = *(const s16x8*)(Wl + ((w >> 1) * 64 + nb * 16 + l15) * 72 + kt * 32 + l4 * 8);
            if (SPLIT) {
                s16x8 afl[4], bfl[4];
#pragma unroll
                for (int mb = 0; mb < 4; mb++)
                    afl[mb] = *(const s16x8*)(Al + LOFS + ((w & 1) * 64 + mb * 16 + l15) * 72 + kt * 32 + l4 * 8);
#pragma unroll
                for (int nb = 0; nb < 4; nb++)
                    bfl[nb] = *(const s16x8*)(Wl + LOFS + ((w >> 1) * 64 + nb * 16 + l15) * 72 + kt * 32 + l4 * 8);
#pragma unroll
                for (int mb = 0; mb < 4; mb++)
#pragma unroll
                    for (int nb = 0; nb < 4; nb++) {
                        acc[mb][nb] = mfma16(afh[mb], bfh[nb], acc[mb][nb]);
                        acc[mb][nb] = mfma16(afh[mb], bfl[nb], acc[mb][nb]);
                        acc[mb][nb] = mfma16(afl[mb], bfh[nb], acc[mb][nb]);
                    }
            } else {
#pragma unroll
                for (int mb = 0; mb < 4; mb++)
#pragma unroll
                    for (int nb = 0; nb < 4; nb++)
                        acc[mb][nb] = mfma16(afh[mb], bfh[nb], acc[mb][nb]);
            }
        }
    }

    const int m0 = bm * 128 + (w & 1) * 64;
    const int n0 = bn * 128 + (w >> 1) * 64;
#pragma unroll
    for (int nb = 0; nb < 4; nb++) {
        float bv = 0.0f;
        const int n = n0 + nb * 16 + l15;
        if (BIAS) bv = bias[n];
#pragma unroll
        for (int mb = 0; mb < 4; mb++) {
#pragma unroll
            for (int i = 0; i < 4; i++) {
                const int m = m0 + mb * 16 + l4 * 4 + i;
                float vv = acc[mb][nb][i];
                if (BIAS) vv += bv;
                if (TANH) vv = tanh_fast(vv);
                if (OUTBF16) ((unsigned short*)outp)[(size_t)m * N + n] = f2bf(vv);
                else        ((float*)outp)[(size_t)m * N + n] = vv;
            }
        }
    }
}

// ---------------------------------------------------------------------------
// Fused attention (unchanged, proven)
// ---------------------------------------------------------------------------
__global__ __launch_bounds__(512, 4)
void att_k(const float* __restrict__ Pt, const float* __restrict__ Qt,
           const float* __restrict__ Vv, const float* __restrict__ vin,
           unsigned short* __restrict__ cbuf)
{
    const int tblk = blockIdx.x, b = blockIdx.y;
    const int tid = threadIdx.x;
    const int w = tid >> 6, lane = tid & 63;
    const int t_in = lane >> 5, sl = lane & 31;
    const int t_loc = w * 2 + t_in;
    const int tg = tblk * 16 + t_loc;

    __shared__ float sbuf[16][513];
    __shared__ float qst[8][640];
    __shared__ float zinv[16];

    float Pa[16], Vb[16], VbA[16];
    {
        const float* pp = Pt + ((size_t)tg * 64 + b) * 512 + sl * 16;
        const float* vb = Vv + (size_t)b * 512 + sl * 16;
#pragma unroll
        for (int j = 0; j < 4; j++) {
            f32x4 x = *(const f32x4*)(pp + j * 4);
            f32x4 y = *(const f32x4*)(vb + j * 4);
#pragma unroll
            for (int e = 0; e < 4; e++) { Pa[j * 4 + e] = x[e]; Vb[j * 4 + e] = y[e]; }
        }
#pragma unroll
        for (int e = 0; e < 16; e++) VbA[e] = Vb[e] * Pa[e];
    }

    for (int l0 = 0; l0 < 512; l0 += 8) {
        __syncthreads();
        {
            const int row = tid >> 6;
            const int cb = (tid & 63) * 8;
            const float* src = Qt + ((size_t)(l0 + row) * 64 + b) * 512 + cb;
            const int f0 = cb + 4 * (cb >> 4);
            *(f32x4*)(&qst[row][f0])     = *(const f32x4*)(src);
            *(f32x4*)(&qst[row][f0 + 4]) = *(const f32x4*)(src + 4);
        }
        __syncthreads();
        for (int l = 0; l < 8; l++) {
            const float* qrow = &qst[l][sl * 20];
            float a0 = 0.f, a1 = 0.f, a2 = 0.f, a3 = 0.f;
#pragma unroll
            for (int j = 0; j < 4; j++) {
                f32x4 q = *(const f32x4*)(qrow + j * 4);
                {
                    float d = fmaf(Pa[4 * j + 0], q[0], 1.0f);
                    a0 = fmaf(fmaf(Vb[4 * j + 0], q[0], VbA[4 * j + 0]), rcp_fast(d), a0);
                }
                {
                    float d = fmaf(Pa[4 * j + 1], q[1], 1.0f);
                    a1 = fmaf(fmaf(Vb[4 * j + 1], q[1], VbA[4 * j + 1]), rcp_fast(d), a1);
                }
                {
                    float d = fmaf(Pa[4 * j + 2], q[2], 1.0f);
                    a2 = fmaf(fmaf(Vb[4 * j + 2], q[2], VbA[4 * j + 2]), rcp_fast(d), a2);
                }
                {
                    float d = fmaf(Pa[4 * j + 3], q[3], 1.0f);
                    a3 = fmaf(fmaf(Vb[4 * j + 3], q[3], VbA[4 * j + 3]), rcp_fast(d), a3);
                }
            }
            float accp = (a0 + a1) + (a2 + a3);
#pragma unroll
            for (int m = 1; m < 32; m <<= 1) accp += __shfl_xor(accp, m, 64);
            if (sl == 0) sbuf[t_loc][l0 + l] = accp;
        }
    }
    __syncthreads();

    {
        const int tr = tid >> 5;
        const int i = tid & 31;
        float m = -1e30f;
        for (int l = i; l < 512; l += 32) m = fmaxf(m, sbuf[tr][l]);
#pragma unroll
        for (int mm = 1; mm < 32; mm <<= 1) m = fmaxf(m, __shfl_xor(m, mm, 64));
        float z = 0.0f;
        for (int l = i; l < 512; l += 32) {
            float e = __expf(sbuf[tr][l] - m);
            sbuf[tr][l] = e;
            z += e;
        }
#pragma unroll
        for (int mm = 1; mm < 32; mm <<= 1) z += __shfl_xor(z, mm, 64);
        if (i == 0) zinv[tr] = rcp_fast(z);
    }
    __syncthreads();

    float ca[16];
#pragma unroll
    for (int j = 0; j < 16; j++) ca[j] = 0.0f;

    for (int l0 = 0; l0 < 512; l0 += 8) {
        __syncthreads();
        {
            const int row = tid >> 6;
            const int cb = (tid & 63) * 8;
            const float* src = vin + ((size_t)(l0 + row) * 64 + b) * 512 + cb;
            const int f0 = cb + 4 * (cb >> 4);
            *(f32x4*)(&qst[row][f0])     = *(const f32x4*)(src);
            *(f32x4*)(&qst[row][f0 + 4]) = *(const f32x4*)(src + 4);
        }
        __syncthreads();
        for (int l = 0; l < 8; l++) {
            const float a = sbuf[t_loc][l0 + l];
            const float* vrow = &qst[l][sl * 20];
#pragma unroll
            for (int j = 0; j < 4; j++) {
                f32x4 x = *(const f32x4*)(vrow + j * 4);
                ca[4 * j + 0] = fmaf(a, x[0], ca[4 * j + 0]);
                ca[4 * j + 1] = fmaf(a, x[1], ca[4 * j + 1]);
                ca[4 * j + 2] = fmaf(a, x[2], ca[4 * j + 2]);
                ca[4 * j + 3] = fmaf(a, x[3], ca[4 * j + 3]);
            }
        }
    }
    const float zi = zinv[t_loc];
    unsigned short* co = cbuf + ((size_t)tg * 64 + b) * 512 + sl * 16;
#pragma unroll
    for (int j = 0; j < 4; j++) {
        s16x4 o;
        o[0] = (short)f2bf(ca[4 * j + 0] * zi);
        o[1] = (short)f2bf(ca[4 * j + 1] * zi);
        o[2] = (short)f2bf(ca[4 * j + 2] * zi);
        o[3] = (short)f2bf(ca[4 * j + 3] * zi);
        *(s16x4*)(co + j * 4) = o;
    }
}

// ---------------------------------------------------------------------------
// rec_k v6. ctrl u32 offsets:
//   barA [0,4096) | xarr [4096,4160) | acnt 4160 | rdy/tflg/vote/done
//   4176/4192/4208/4224 (+8 each) | test 4352+g*32 | barL2 [4608,8704)
//   barD [8704,12800)  (demote arrival counters, agent-scope)
// ---------------------------------------------------------------------------
#define C_BAR   0
#define C_XARR  4096
#define C_ACNT  4160
#define C_RDY   4176
#define C_TFLG  4192
#define C_VOTE  4208
#define C_DONE  4224
#define C_TEST  4352
#define C_BARL2 4608
#define C_BARD  8704
#define MAGIC   0x5A5AA5A5u
#define HWREG_XCC_ID (20 | (31 << 11))

__global__ __launch_bounds__(256, 1)
void rec_k(const unsigned short* __restrict__ Gi,
           const float* __restrict__ Whh, const float* __restrict__ bhh,
           const float* __restrict__ h0,
           unsigned int* __restrict__ hb32,
           unsigned int* __restrict__ ctrl,
           float* __restrict__ hs)
{
    const int tid = threadIdx.x;
    const int bid = blockIdx.x;
    __shared__ int sh_g, sh_sub, sh_fast;
    __shared__ unsigned sh_xv[64];

    // ---------- deterministic grouping + probe (r6-proven; all polls guaranteed) ----------
    if (tid == 0) {
        const unsigned xcd = ((unsigned)__builtin_amdgcn_s_getreg(HWREG_XCC_ID)) & 7u;
        unsigned* xarr = ctrl + C_XARR;
        unsigned* acnt = ctrl + C_ACNT;
        st_agent(&xarr[bid], 0x100u | xcd);
        vm_drain();
        add_agent(acnt, 1u);
        poll_agent_ge(acnt, 64u);
        for (int i = 0; i < 64; i++) sh_xv[i] = ld_agent(&xarr[i]) & 7u;

        int rank = 0;
        for (int i = 0; i < 64; i++)
            if (sh_xv[i] < xcd || (sh_xv[i] == xcd && i < bid)) rank++;
        const int g = rank >> 3, sub = rank & 7;

        int uni = 1;
        {
            unsigned gx = 0xFFu;
            for (int i = 0; i < 64; i++) {
                int ri = 0;
                for (int j = 0; j < 64; j++)
                    if (sh_xv[j] < sh_xv[i] || (sh_xv[j] == sh_xv[i] && j < i)) ri++;
                if ((ri >> 3) == g) {
                    if (gx == 0xFFu) gx = sh_xv[i];
                    else if (sh_xv[i] != gx) uni = 0;
                }
            }
        }

        unsigned* rdy  = ctrl + C_RDY;
        unsigned* tflg = ctrl + C_TFLG;
        unsigned* vote = ctrl + C_VOTE;
        unsigned* done = ctrl + C_DONE;
        unsigned* test = ctrl + C_TEST + g * 32;
        unsigned saw;
        if (sub != 0) {
            unsigned pr = ld_plain_wait(test);
            asm volatile("" :: "v"(pr));
            add_agent(&rdy[g], 1u);
            poll_agent_ge(&tflg[g], 1u);
            unsigned u = ld_u32_sc0_wait(test);
            saw = (u == MAGIC) ? 1u : 0u;
        } else {
            poll_agent_ge(&rdy[g], 7u);
            st_plain(test, MAGIC);
            vm_drain();
            add_agent(&tflg[g], 1u);
            saw = 1u;
        }
        add_agent(&vote[g], saw);
        vm_drain();
        add_agent(&done[g], 1u);
        poll_agent_ge(&done[g], 8u);
        sh_fast = (uni && ld_agent(&vote[g]) == 8u) ? 1 : 0;
        sh_g = g; sh_sub = sub;
    }
    __syncthreads();
    const int g = sh_g, sub = sh_sub;
    int fast = sh_fast;

    // ---------- geometry ----------
    const int w = tid >> 6;
    const int lane = tid & 63;
    const int l15 = lane & 15, l4 = lane >> 4;
    const int b  = g * 8 + (l15 & 7);
    const int jb = sub * 64 + w * 16;
    const int jrow = l4 * 4;
    const bool writer = (l15 < 8);

    s16x8 wf[3][16];
#pragma unroll
    for (int gg = 0; gg < 3; gg++) {
        const float* wr = Whh + (size_t)(gg * 512 + jb + l15) * 512 + l4 * 8;
#pragma unroll
        for (int c = 0; c < 16; c++) {
            f32x4 x = *(const f32x4*)(wr + c * 32);
            f32x4 y = *(const f32x4*)(wr + c * 32 + 4);
            wf[gg][c] = pack8(x, y);
        }
    }

    float bh_r[4], bh_z[4], bh_n[4];
#pragma unroll
    for (int i = 0; i < 4; i++) {
        bh_r[i] = bhh[jb + jrow + i];
        bh_z[i] = bhh[512 + jb + jrow + i];
        bh_n[i] = bhh[1024 + jb + jrow + i];
    }
    float hp[4];
#pragma unroll
    for (int i = 0; i < 4; i++) hp[i] = h0[(size_t)b * 512 + jb + jrow + i];

    unsigned* barA  = ctrl + C_BAR   + g * 512;
    unsigned* barL2 = ctrl + C_BARL2 + g * 512;
    unsigned* barD  = ctrl + C_BARD  + g * 512;

    s16x4 g0, g1, g2;
    {
        const unsigned short* gp = Gi + (size_t)b * 1536 + jb + jrow;
        g0 = *(const s16x4*)(gp);
        g1 = *(const s16x4*)(gp + 512);
        g2 = *(const s16x4*)(gp + 1024);
    }

#define LDH(i, lit) asm volatile("global_load_dwordx4 %0, %1, off offset:" lit " sc0" \
                                 : "=v"(hfrag[i]) : "v"(src) : "memory");

    for (int t = 0; t < 512; t++) {
        s16x8 hfrag[16];
        if (t == 0) {
            const float* hr = h0 + (size_t)b * 512 + l4 * 8;
#pragma unroll
            for (int c = 0; c < 16; c++) {
                f32x4 x = *(const f32x4*)(hr + c * 32);
                f32x4 y = *(const f32x4*)(hr + c * 32 + 4);
                hfrag[c] = pack8(x, y);
            }
        } else if (fast) {
            const unsigned int* src = hb32 + (t & 1) * 16384 + b * 256 + l4 * 4;
            LDH(0, "0")   LDH(1, "64")  LDH(2, "128")  LDH(3, "192")
            LDH(4, "256") LDH(5, "320") LDH(6, "384")  LDH(7, "448")
            LDH(8, "512") LDH(9, "576") LDH(10, "640") LDH(11, "704")
            LDH(12, "768") LDH(13, "832") LDH(14, "896") LDH(15, "960")
            vm_drain();
            __builtin_amdgcn_sched_barrier(0);
        } else {
            const unsigned int* src = hb32 + (t & 1) * 16384 + b * 256 + l4 * 4;
#pragma unroll
            for (int c = 0; c < 16; c++) {
                union { unsigned int u[4]; s16x8 v; } cv;
#pragma unroll
                for (int q = 0; q < 4; q++)
                    cv.u[q] = ld_agent(src + c * 16 + q);
                hfrag[c] = cv.v;
            }
        }

        f32x4 acc0 = {0.f, 0.f, 0.f, 0.f};
        f32x4 acc1 = {0.f, 0.f, 0.f, 0.f};
        f32x4 acc2 = {0.f, 0.f, 0.f, 0.f};
#pragma unroll
        for (int c = 0; c < 16; c++) {
            acc0 = mfma16(wf[0][c], hfrag[c], acc0);
            acc1 = mfma16(wf[1][c], hfrag[c], acc1);
            acc2 = mfma16(wf[2][c], hfrag[c], acc2);
        }

#pragma unroll
        for (int i = 0; i < 4; i++) {
            float rr = sigmoid_fast(bf2f((unsigned short)g0[i]) + acc0[i] + bh_r[i]);
            float zz = sigmoid_fast(bf2f((unsigned short)g1[i]) + acc1[i] + bh_z[i]);
            float nn = tanh_fast(bf2f((unsigned short)g2[i]) + rr * (acc2[i] + bh_n[i]));
            hp[i] = fmaf(zz, hp[i] - nn, nn);
        }

        float* hso = hs + ((size_t)t * 64 + b) * 512 + jb + jrow;
        f32x4 hv = {hp[0], hp[1], hp[2], hp[3]};

        if (t < 511) {
            const unsigned p0 = (unsigned)f2bf(hp[0]) | ((unsigned)f2bf(hp[1]) << 16);
            const unsigned p1 = (unsigned)f2bf(hp[2]) | ((unsigned)f2bf(hp[3]) << 16);
            unsigned int* dst = hb32 + ((t + 1) & 1) * 16384 + b * 256 + ((jb + jrow) >> 1);
            if (writer) {
                if (fast) { u32x2 pp = {p0, p1}; *(u32x2*)dst = pp; }
                else { st_agent(dst, p0); st_agent(dst + 1, p1); }
            }
            vm_drain();
            __syncthreads();                       // bar1: all waves' h stores ACKed
            if (tid == 0) {
                if (fast) atomic_add_l2(barL2 + t, 1u);
                else      add_agent(barA + t, 1u);
            }

            // hidden under the wait: hs store (PLAIN -> L2 ack) + Gi prefetch
            if (writer) *(f32x4*)hso = hv;
            s16x4 n0, n1, n2;
            {
                const unsigned short* gp = Gi + ((size_t)(t + 1) * 64 + b) * 1536 + jb + jrow;
                n0 = *(const s16x4*)(gp);
                n1 = *(const s16x4*)(gp + 512);
                n2 = *(const s16x4*)(gp + 1024);
            }

            if (fast) {
                // per-wave poll: plain sc0 LOADS (readers don't serialize)
                bool ok = false;
                unsigned it = 0;
                for (;;) {
                    unsigned v = 0;
                    if (lane == 0) v = ld_u32_sc0_wait(barL2 + t);
                    v = (unsigned)__shfl((int)v, 0, 64);
                    if (v >= 8u) { ok = true; break; }
                    if (++it >= 4096u) break;      // watchdog
                    __builtin_amdgcn_s_sleep(1);
                }
                if (!ok) {
                    // demote round: republish agent-scope, per-wave barD add (target 32),
                    // poll both. Split group: barL2 can never reach 8 in one L2 copy ->
                    // all waves demote -> exit via barD (uniform slow). Healthy group:
                    // barL2 reaches 8 -> exit fast.
                    if (writer) { st_agent(dst, p0); st_agent(dst + 1, p1); }
                    vm_drain();
                    if (lane == 0) add_agent(barD + t, 1u);
                    for (;;) {
                        unsigned v1 = 0, v2 = 0;
                        if (lane == 0) {
                            v1 = ld_u32_sc0_wait(barL2 + t);
                            v2 = ld_agent(barD + t);
                        }
                        v1 = (unsigned)__shfl((int)v1, 0, 64);
                        v2 = (unsigned)__shfl((int)v2, 0, 64);
                        if (v1 >= 8u) break;                        // fast after all
                        if (v2 >= 32u) { fast = 0; break; }         // permanent demote
                        __builtin_amdgcn_s_sleep(2);
                    }
                }
            } else {
                for (;;) {
                    unsigned v = 0;
                    if (lane == 0) v = ld_agent(barA + t);
                    v = (unsigned)__shfl((int)v, 0, 64);
                    if (v >= 8u) break;
                    __builtin_amdgcn_s_sleep(1);
                }
            }
            g0 = n0; g1 = n1; g2 = n2;
        } else {
            if (writer) *(f32x4*)hso = hv;
        }
    }
#undef LDH
}

// ---------------------------------------------------------------------------
// ws layout (bytes):
//   Pt  : [0, 64Mi)        f32   Qt: [64Mi,128Mi)   c: [128Mi,160Mi) bf16
//   Gi  : [0, 96Mi)        bf16 (overlays Pt/Qt, dead by then)
//   hb32: [160Mi, +128Ki)  u32 bf16-pairs
//   ctrl: [160Mi+128Ki, +51200B)
// ---------------------------------------------------------------------------
extern "C" void kernel_launch(void* const* d_in, const int* in_sizes, int n_in,
                              void* d_out, int out_size, void* d_ws, size_t ws_size,
                              hipStream_t stream)
{
    (void)in_sizes; (void)n_in; (void)out_size; (void)ws_size;
    const float* v   = (const float*)d_in[0];
    const float* h0  = (const float*)d_in[1];
    const float* Vv  = (const float*)d_in[2];
    const float* Wp  = (const float*)d_in[3];
    const float* Wp_ = (const float*)d_in[4];
    const float* Wih = (const float*)d_in[5];
    const float* Whh = (const float*)d_in[6];
    const float* bih = (const float*)d_in[7];
    const float* bhh = (const float*)d_in[8];
    float* hs = (float*)d_out;

    char* ws = (char*)d_ws;
    float* Pt = (float*)(ws);
    float* Qt = (float*)(ws + 67108864ULL);
    unsigned short* cb  = (unsigned short*)(ws + 134217728ULL);
    unsigned short* Gi  = (unsigned short*)(ws);
    unsigned int*   hb32 = (unsigned int*)(ws + 167772160ULL);
    unsigned int*   ctrl = (unsigned int*)(ws + 167772160ULL + 131072ULL);

    hipMemsetAsync(ctrl, 0, 12800 * sizeof(unsigned int), stream);

    dim3 gpq(256, 4, 1);
    gemm_k<1, 1, 0, 0, 0><<<gpq, 256, 0, stream>>>(v, Wp, nullptr, Pt, 32768, 512);
    gemm_k<1, 1, 0, 0, 0><<<gpq, 256, 0, stream>>>(v, Wp_, nullptr, Qt, 32768, 512);

    att_k<<<dim3(32, 64), 512, 0, stream>>>(Pt, Qt, Vv, v, cb);

    gemm_k<0, 0, 1, 1, 1><<<dim3(256, 12), 256, 0, stream>>>(cb, Wih, bih, Gi, 32768, 1536);

    rec_k<<<dim3(64), 256, 0, stream>>>(Gi, Whh, bhh, h0, hb32, ctrl, hs);
}